// Round 11
// baseline (96.816 us; speedup 1.0000x reference)
//
#include <hip/hip_runtime.h>
#include <hip/hip_fp16.h>
#include <math.h>
#include <stdint.h>

#define U 50
#define TT 100
#define BB 256

typedef _Float16 f16x8 __attribute__((ext_vector_type(8)));
typedef int      i32x4 __attribute__((ext_vector_type(4)));
typedef float    f32x4 __attribute__((ext_vector_type(4)));

__device__ __forceinline__ float sigmoid_fast(float x) {
    return 1.0f / (1.0f + __expf(-x));   // saturates cleanly, no NaN
}
__device__ __forceinline__ float tanh_fast(float x) {
    float e = __expf(2.0f * x);
    return 1.0f - 2.0f / (e + 1.0f);     // saturates cleanly, no NaN
}
__device__ __forceinline__ float param_act(float x, float mn, float mx) {
    float scale = 0.5f * (mx - mn);
    return tanh_fast(x) * scale + mn + scale;
}

// One wave per batch element. Per step the recurrent GEMV runs as 32 MFMA
// intrinsics (hazards compiler-managed):
//   z_rec(1x256) = [h | 0](1x64) @ [rec ; 0](64x256)
// B-fragments live in 128 AGPRs (staged once, pinned "+a"; MFMA reads AGPR
// natively on gfx950 -> zero per-step weight traffic on any pipe). The x-part
// (zx = x@kernel + bias) stays in f32 VALU for precision. A-operand: h~
// broadcast across rows via 2 ds_read_b128; k-map (e = k-8q, contiguous) is
// identical on A and B so any hardware k-permutation cancels. D rows are
// redundant; lane (c,q) takes tile nt=q, col c -> gate math fully lane-local,
// one ds_write_b16 refills h. Single wave -> zero barriers.
__global__ __launch_bounds__(64, 1) void encoder_kernel(
    const float* __restrict__ x,        // (B,T,4)
    const float* __restrict__ state,    // (B,T,4)
    const float* __restrict__ kernel,   // (4,200)
    const float* __restrict__ rec,      // (50,200)
    const float* __restrict__ bias,     // (200,)
    const float* __restrict__ w_dv, const float* __restrict__ b_dv,
    const float* __restrict__ w_dt, const float* __restrict__ b_dt,
    const float* __restrict__ w_mj, const float* __restrict__ b_mj,
    const float* __restrict__ w_ma, const float* __restrict__ b_ma,
    const float* __restrict__ w_mi, const float* __restrict__ b_mi,
    float* __restrict__ out)            // act_seq (B*T) then idm (B*5)
{
    const int b = blockIdx.x;
    const int l = threadIdx.x;
    const int c = l & 15;
    const int q = l >> 4;
    const int u = 16 * q + c;           // unit owned by this lane (u<50 active)

    __shared__ __align__(16) _Float16 h16[64];  // [0:50) h, rest stays 0
    __shared__ float idm[8];

    // ---- stage W~ fragments into AGPRs (once) ----
    // wf[g][nt][ks] elem e = W~[k = 32*ks + 8*q + e][col = 16*nt + c]
    i32x4 wf[4][4][2];
    #pragma unroll
    for (int g = 0; g < 4; ++g) {
        #pragma unroll
        for (int nt = 0; nt < 4; ++nt) {
            const int uu = 16 * nt + c;
            #pragma unroll
            for (int ks = 0; ks < 2; ++ks) {
                f16x8 f;
                #pragma unroll
                for (int e = 0; e < 8; ++e) {
                    int j = 32 * ks + 8 * q + e;
                    float v = 0.0f;
                    if (uu < U && j < U) v = rec[j * 200 + g * U + uu];
                    f[e] = (_Float16)v;
                }
                wf[g][nt][ks] = __builtin_bit_cast(i32x4, f);
            }
        }
    }
    #pragma unroll
    for (int g = 0; g < 4; ++g)
        #pragma unroll
        for (int nt = 0; nt < 4; ++nt) {
            asm volatile("" : "+a"(wf[g][nt][0]));
            asm volatile("" : "+a"(wf[g][nt][1]));
        }

    // ---- x-path weights in f32 (precision-critical, small) ----
    const int cl = (u < U) ? u : (U - 1);
    float kc[16];
    #pragma unroll
    for (int g = 0; g < 4; ++g)
        #pragma unroll
        for (int f = 0; f < 4; ++f)
            kc[g * 4 + f] = kernel[f * 200 + g * U + cl];
    float bz[4];
    #pragma unroll
    for (int g = 0; g < 4; ++g) bz[g] = bias[g * U + cl];

    h16[l] = (_Float16)0.0f;
    float cstate = 0.0f;

    const float4* __restrict__ xb4 = (const float4*)(x + (size_t)b * TT * 4);
    const uint4* __restrict__ hq = (const uint4*)h16;   // 8 chunks of 8 f16

    float4 x4 = xb4[0];
    const f32x4 zero4 = {0.f, 0.f, 0.f, 0.f};

    for (int t = 0; t < TT; ++t) {
        float4 x4n = xb4[(t + 1 < TT) ? (t + 1) : t];  // prefetch, used next iter

        // A-operand: 2 broadcast ds_read_b128; elem e = h~[32*ks + 8q + e]
        uint4 a0u = hq[q];
        uint4 a1u = hq[4 + q];
        f16x8 A0 = __builtin_bit_cast(f16x8, a0u);
        f16x8 A1 = __builtin_bit_cast(f16x8, a1u);

        // x-part in f32 (independent of h -> fills LDS latency shadow)
        float zx[4];
        #pragma unroll
        for (int g = 0; g < 4; ++g) {
            zx[g] = fmaf(x4.x, kc[g * 4 + 0],
                    fmaf(x4.y, kc[g * 4 + 1],
                    fmaf(x4.z, kc[g * 4 + 2],
                    fmaf(x4.w, kc[g * 4 + 3], bz[g]))));
        }

        // 32 MFMAs (intrinsic: hazards + AGPR-B handled by compiler)
        float z[4];
        #pragma unroll
        for (int g = 0; g < 4; ++g) {
            f32x4 a0 = __builtin_amdgcn_mfma_f32_16x16x32_f16(
                A0, __builtin_bit_cast(f16x8, wf[g][0][0]), zero4, 0, 0, 0);
            f32x4 a1 = __builtin_amdgcn_mfma_f32_16x16x32_f16(
                A0, __builtin_bit_cast(f16x8, wf[g][1][0]), zero4, 0, 0, 0);
            f32x4 a2 = __builtin_amdgcn_mfma_f32_16x16x32_f16(
                A0, __builtin_bit_cast(f16x8, wf[g][2][0]), zero4, 0, 0, 0);
            f32x4 a3 = __builtin_amdgcn_mfma_f32_16x16x32_f16(
                A0, __builtin_bit_cast(f16x8, wf[g][3][0]), zero4, 0, 0, 0);
            a0 = __builtin_amdgcn_mfma_f32_16x16x32_f16(
                A1, __builtin_bit_cast(f16x8, wf[g][0][1]), a0, 0, 0, 0);
            a1 = __builtin_amdgcn_mfma_f32_16x16x32_f16(
                A1, __builtin_bit_cast(f16x8, wf[g][1][1]), a1, 0, 0, 0);
            a2 = __builtin_amdgcn_mfma_f32_16x16x32_f16(
                A1, __builtin_bit_cast(f16x8, wf[g][2][1]), a2, 0, 0, 0);
            a3 = __builtin_amdgcn_mfma_f32_16x16x32_f16(
                A1, __builtin_bit_cast(f16x8, wf[g][3][1]), a3, 0, 0, 0);
            // lane (c,q) needs tile nt=q, col c; D rows redundant -> reg 0
            float zz = (q == 0) ? a0[0] : (q == 1) ? a1[0]
                     : (q == 2) ? a2[0] : a3[0];
            z[g] = zz + zx[g];
        }

        float ig = sigmoid_fast(z[0]);
        float fg = sigmoid_fast(z[1]);
        float gg = tanh_fast(z[2]);
        float og = sigmoid_fast(z[3]);
        cstate = fmaf(fg, cstate, ig * gg);
        float hnew = og * tanh_fast(cstate);
        if (u < U) h16[u] = (_Float16)hnew;

        x4 = x4n;
        // no barrier: single wave, in-order LDS pipeline + compiler lgkmcnt
    }

    // ---- 5 output heads (lanes 0..4) ----
    if (l < 5) {
        const float* w  = (l == 0) ? w_dv : (l == 1) ? w_dt :
                          (l == 2) ? w_mj : (l == 3) ? w_ma : w_mi;
        const float* bb = (l == 0) ? b_dv : (l == 1) ? b_dt :
                          (l == 2) ? b_mj : (l == 3) ? b_ma : b_mi;
        float s = bb[0];
        #pragma unroll
        for (int j = 0; j < U; ++j) s = fmaf((float)h16[j], w[j], s);
        float v;
        if (l == 0)      v = param_act(s, 15.0f, 35.0f);
        else if (l == 1) v = param_act(s, 0.5f, 3.0f);
        else if (l == 2) v = fmaxf(s, 0.0f);
        else if (l == 3) v = param_act(s, 0.5f, 3.0f);
        else             v = param_act(s, 0.5f, 4.0f);
        idm[l] = v;
        out[BB * TT + b * 5 + l] = v;
    }

    // ---- IDM physics over T ----
    const float desired_v    = idm[0];
    const float desired_tgap = idm[1];
    const float min_jamx     = idm[2];
    const float max_act      = idm[3];
    const float min_act      = idm[4];
    const float inv_tsab = 1.0f / (2.0f * sqrtf(max_act * min_act));
    const float inv_dv   = 1.0f / desired_v;

    const float4* __restrict__ sb4 = (const float4*)(state + (size_t)b * TT * 4);
    for (int t = l; t < TT; t += 64) {
        float4 s4 = sb4[t];
        float vel = s4.x;
        float dv  = s4.z;
        float dx  = s4.w;
        float dgap = fmaf(desired_tgap, vel, fmaf(vel * dv, inv_tsab, min_jamx));
        float r1 = vel * inv_dv;
        r1 = r1 * r1;
        r1 = r1 * r1;            // ^4
        float r2 = dgap / dx;
        r2 = r2 * r2;            // ^2
        out[b * TT + t] = max_act * (1.0f - (r1 + r2));
    }
}

extern "C" void kernel_launch(void* const* d_in, const int* in_sizes, int n_in,
                              void* d_out, int out_size, void* d_ws, size_t ws_size,
                              hipStream_t stream) {
    const float* x      = (const float*)d_in[0];
    const float* state  = (const float*)d_in[1];
    const float* kern   = (const float*)d_in[2];
    const float* rec    = (const float*)d_in[3];
    const float* bias   = (const float*)d_in[4];
    const float* w_dv   = (const float*)d_in[5];
    const float* b_dv   = (const float*)d_in[6];
    const float* w_dt   = (const float*)d_in[7];
    const float* b_dt   = (const float*)d_in[8];
    const float* w_mj   = (const float*)d_in[9];
    const float* b_mj   = (const float*)d_in[10];
    const float* w_ma   = (const float*)d_in[11];
    const float* b_ma   = (const float*)d_in[12];
    const float* w_mi   = (const float*)d_in[13];
    const float* b_mi   = (const float*)d_in[14];
    float* out = (float*)d_out;

    encoder_kernel<<<BB, 64, 0, stream>>>(
        x, state, kern, rec, bias,
        w_dv, b_dv, w_dt, b_dt, w_mj, b_mj, w_ma, b_ma, w_mi, b_mi,
        out);
}

// Round 12
// 89.806 us; speedup vs baseline: 1.0781x; 1.0781x over previous
//
#include <hip/hip_runtime.h>
#include <hip/hip_fp16.h>
#include <math.h>
#include <stdint.h>

#define U 50
#define TT 100
#define BB 256

typedef _Float16 half2v __attribute__((ext_vector_type(2)));

__device__ __forceinline__ float dot2_acc(uint32_t w, uint32_t h_uniform, float c) {
#if __has_builtin(__builtin_amdgcn_fdot2)
    return __builtin_amdgcn_fdot2(__builtin_bit_cast(half2v, w),
                                  __builtin_bit_cast(half2v, h_uniform), c, false);
#else
    half2v a = __builtin_bit_cast(half2v, w);
    half2v b = __builtin_bit_cast(half2v, h_uniform);
    return fmaf((float)a.x, (float)b.x, fmaf((float)a.y, (float)b.y, c));
#endif
}

__device__ __forceinline__ float sigmoid_fast(float x) {
    return 1.0f / (1.0f + __expf(-x));   // saturates cleanly, no NaN
}
__device__ __forceinline__ float tanh_fast(float x) {
    float e = __expf(2.0f * x);
    return 1.0f - 2.0f / (e + 1.0f);     // saturates cleanly, no NaN
}
__device__ __forceinline__ float param_act(float x, float mn, float mx) {
    float scale = 0.5f * (mx - mn);
    return tanh_fast(x) * scale + mn + scale;
}

// One wave per batch element; lane l (<50) owns LSTM unit l (4 gate columns
// as 100 packed-f16 dwords, asm-pinned like round 4). NEW: the h exchange
// uses NO LDS -- h(t) is broadcast via 50 v_readlane into SGPRs, packed into
// 25 uniform f16-pairs on the SALU pipe, and consumed as the SGPR operand of
// v_dot2_f32_f16. The recurrence loop never touches LDS or a barrier.
__global__ __launch_bounds__(64, 1) void encoder_kernel(
    const float* __restrict__ x,        // (B,T,4)
    const float* __restrict__ state,    // (B,T,4)
    const float* __restrict__ kernel,   // (4,200)
    const float* __restrict__ rec,      // (50,200)
    const float* __restrict__ bias,     // (200,)
    const float* __restrict__ w_dv, const float* __restrict__ b_dv,
    const float* __restrict__ w_dt, const float* __restrict__ b_dt,
    const float* __restrict__ w_mj, const float* __restrict__ b_mj,
    const float* __restrict__ w_ma, const float* __restrict__ b_ma,
    const float* __restrict__ w_mi, const float* __restrict__ b_mi,
    float* __restrict__ out)            // act_seq (B*T) then idm (B*5)
{
    const int b = blockIdx.x;
    const int l = threadIdx.x;
    const int cl = (l < U) ? l : (U - 1);   // clamped column lane

    __shared__ __align__(16) _Float16 h16[64];  // used only AFTER the loop
    __shared__ float idm[8];

    // rcpu[g*25+j] = packed( rec[2j][g*50+cl], rec[2j+1][g*50+cl] )
    uint32_t rcpu[100];
    #pragma unroll
    for (int g = 0; g < 4; ++g) {
        #pragma unroll
        for (int j = 0; j < 25; ++j) {
            float r0 = rec[(2 * j) * 200 + g * U + cl];
            float r1 = rec[(2 * j + 1) * 200 + g * U + cl];
            half2v p; p.x = (_Float16)r0; p.y = (_Float16)r1;
            rcpu[g * 25 + j] = __builtin_bit_cast(uint32_t, p);
        }
    }
    #pragma unroll
    for (int j = 0; j < 100; ++j) asm volatile("" : "+v"(rcpu[j]));

    // x-path weights in f32 (precision-critical, small)
    float kc[16];
    #pragma unroll
    for (int g = 0; g < 4; ++g)
        #pragma unroll
        for (int f = 0; f < 4; ++f)
            kc[g * 4 + f] = kernel[f * 200 + g * U + cl];
    float bz[4];
    #pragma unroll
    for (int g = 0; g < 4; ++g) bz[g] = bias[g * U + cl];

    float cstate = 0.0f;
    uint32_t vhu = 0;          // this lane's h as f16 bits (h(0) = 0)

    const float4* __restrict__ xb4 = (const float4*)(x + (size_t)b * TT * 4);
    float4 x4 = xb4[0];

    float hnew_f = 0.0f;       // f32 copy of own h (for post-loop LDS store)

    for (int t = 0; t < TT; ++t) {
        float4 x4n = xb4[(t + 1 < TT) ? (t + 1) : t];  // prefetch, used next iter

        // ---- broadcast h(t): 50 readlanes -> SGPRs, pack pairs on SALU ----
        uint32_t rl[U];
        #pragma unroll
        for (int j = 0; j < U; ++j) rl[j] = __builtin_amdgcn_readlane(vhu, j);
        uint32_t hp[25];
        #pragma unroll
        for (int j = 0; j < 25; ++j)
            hp[j] = (rl[2 * j + 1] << 16) | (rl[2 * j] & 0xffffu);

        // ---- x-part in f32 (independent of h) ----
        float zx[4];
        #pragma unroll
        for (int g = 0; g < 4; ++g) {
            zx[g] = fmaf(x4.x, kc[g * 4 + 0],
                    fmaf(x4.y, kc[g * 4 + 1],
                    fmaf(x4.z, kc[g * 4 + 2],
                    fmaf(x4.w, kc[g * 4 + 3], bz[g]))));
        }

        // ---- 100 v_dot2_f32_f16, weights VGPR x h-pair SGPR ----
        float acc[8] = {0.f, 0.f, 0.f, 0.f, 0.f, 0.f, 0.f, 0.f};
        #pragma unroll
        for (int j = 0; j < 25; ++j) {
            const int s = (j & 1) * 4;
            acc[s + 0] = dot2_acc(rcpu[0 * 25 + j], hp[j], acc[s + 0]);
            acc[s + 1] = dot2_acc(rcpu[1 * 25 + j], hp[j], acc[s + 1]);
            acc[s + 2] = dot2_acc(rcpu[2 * 25 + j], hp[j], acc[s + 2]);
            acc[s + 3] = dot2_acc(rcpu[3 * 25 + j], hp[j], acc[s + 3]);
        }

        float zi = zx[0] + acc[0] + acc[4];
        float zf = zx[1] + acc[1] + acc[5];
        float zg = zx[2] + acc[2] + acc[6];
        float zo = zx[3] + acc[3] + acc[7];

        float ig = sigmoid_fast(zi);
        float fg = sigmoid_fast(zf);
        float gg = tanh_fast(zg);
        float og = sigmoid_fast(zo);
        cstate = fmaf(fg, cstate, ig * gg);
        hnew_f = og * tanh_fast(cstate);
        _Float16 hf = (_Float16)hnew_f;
        vhu = (uint32_t)__builtin_bit_cast(unsigned short, hf);

        x4 = x4n;
        // no LDS, no barrier: the whole exchange is readlane/SALU
    }

    // ---- stash h(T) to LDS once for the (unchanged) epilogue ----
    if (l < U) h16[l] = (_Float16)hnew_f;
    if (l >= U) h16[l] = (_Float16)0.0f;

    // ---- 5 output heads (lanes 0..4) ----
    if (l < 5) {
        const float* w  = (l == 0) ? w_dv : (l == 1) ? w_dt :
                          (l == 2) ? w_mj : (l == 3) ? w_ma : w_mi;
        const float* bb = (l == 0) ? b_dv : (l == 1) ? b_dt :
                          (l == 2) ? b_mj : (l == 3) ? b_ma : b_mi;
        float s = bb[0];
        #pragma unroll
        for (int j = 0; j < U; ++j) s = fmaf((float)h16[j], w[j], s);
        float v;
        if (l == 0)      v = param_act(s, 15.0f, 35.0f);
        else if (l == 1) v = param_act(s, 0.5f, 3.0f);
        else if (l == 2) v = fmaxf(s, 0.0f);
        else if (l == 3) v = param_act(s, 0.5f, 3.0f);
        else             v = param_act(s, 0.5f, 4.0f);
        idm[l] = v;
        out[BB * TT + b * 5 + l] = v;
    }

    // ---- IDM physics over T ----
    const float desired_v    = idm[0];
    const float desired_tgap = idm[1];
    const float min_jamx     = idm[2];
    const float max_act      = idm[3];
    const float min_act      = idm[4];
    const float inv_tsab = 1.0f / (2.0f * sqrtf(max_act * min_act));
    const float inv_dv   = 1.0f / desired_v;

    const float4* __restrict__ sb4 = (const float4*)(state + (size_t)b * TT * 4);
    for (int t = l; t < TT; t += 64) {
        float4 s4 = sb4[t];
        float vel = s4.x;
        float dv  = s4.z;
        float dx  = s4.w;
        float dgap = fmaf(desired_tgap, vel, fmaf(vel * dv, inv_tsab, min_jamx));
        float r1 = vel * inv_dv;
        r1 = r1 * r1;
        r1 = r1 * r1;            // ^4
        float r2 = dgap / dx;
        r2 = r2 * r2;            // ^2
        out[b * TT + t] = max_act * (1.0f - (r1 + r2));
    }
}

extern "C" void kernel_launch(void* const* d_in, const int* in_sizes, int n_in,
                              void* d_out, int out_size, void* d_ws, size_t ws_size,
                              hipStream_t stream) {
    const float* x      = (const float*)d_in[0];
    const float* state  = (const float*)d_in[1];
    const float* kern   = (const float*)d_in[2];
    const float* rec    = (const float*)d_in[3];
    const float* bias   = (const float*)d_in[4];
    const float* w_dv   = (const float*)d_in[5];
    const float* b_dv   = (const float*)d_in[6];
    const float* w_dt   = (const float*)d_in[7];
    const float* b_dt   = (const float*)d_in[8];
    const float* w_mj   = (const float*)d_in[9];
    const float* b_mj   = (const float*)d_in[10];
    const float* w_ma   = (const float*)d_in[11];
    const float* b_ma   = (const float*)d_in[12];
    const float* w_mi   = (const float*)d_in[13];
    const float* b_mi   = (const float*)d_in[14];
    float* out = (float*)d_out;

    encoder_kernel<<<BB, 64, 0, stream>>>(
        x, state, kern, rec, bias,
        w_dv, b_dv, w_dt, b_dt, w_mj, b_mj, w_ma, b_ma, w_mi, b_mi,
        out);
}

// Round 13
// 50.057 us; speedup vs baseline: 1.9341x; 1.7941x over previous
//
#include <hip/hip_runtime.h>
#include <hip/hip_fp16.h>
#include <math.h>
#include <stdint.h>

#define U 50
#define TT 100
#define BB 256

typedef _Float16 half2v __attribute__((ext_vector_type(2)));

__device__ __forceinline__ float dot2_acc(uint32_t h2, uint32_t w2, float c) {
#if __has_builtin(__builtin_amdgcn_fdot2)
    return __builtin_amdgcn_fdot2(__builtin_bit_cast(half2v, h2),
                                  __builtin_bit_cast(half2v, w2), c, false);
#else
    half2v a = __builtin_bit_cast(half2v, h2);
    half2v b = __builtin_bit_cast(half2v, w2);
    return fmaf((float)a.x, (float)b.x, fmaf((float)a.y, (float)b.y, c));
#endif
}

__device__ __forceinline__ float sigmoid_fast(float x) {
    return 1.0f / (1.0f + __expf(-x));   // saturates cleanly, no NaN
}
__device__ __forceinline__ float tanh_fast(float x) {
    float e = __expf(2.0f * x);
    return 1.0f - 2.0f / (e + 1.0f);     // saturates cleanly, no NaN
}
__device__ __forceinline__ float param_act(float x, float mn, float mx) {
    float scale = 0.5f * (mx - mn);
    return tanh_fast(x) * scale + mn + scale;
}

// TWO waves per batch element, gate-split to halve the per-lane weight
// footprint (the rounds-2..11 lesson: hipcc keeps <=~50-80 loop-invariant
// dwords resident, never ~100). Wave 0 lane l owns gates (i,f) of unit l;
// wave 1 owns (g,o). 50 dot2/lane/step. Wave 1 finishes tanh(zg)/sig(zo)
// pre-barrier and ships one float2; wave 0 does the c/h chain post-barrier.
// x is pre-staged in LDS so the loop has ZERO VMEM -> barrier drains cost
// nothing beyond lgkmcnt (round-7 lesson).
__global__ __launch_bounds__(128, 1) void encoder_kernel(
    const float* __restrict__ x,        // (B,T,4)
    const float* __restrict__ state,    // (B,T,4)
    const float* __restrict__ kernel,   // (4,200)
    const float* __restrict__ rec,      // (50,200)
    const float* __restrict__ bias,     // (200,)
    const float* __restrict__ w_dv, const float* __restrict__ b_dv,
    const float* __restrict__ w_dt, const float* __restrict__ b_dt,
    const float* __restrict__ w_mj, const float* __restrict__ b_mj,
    const float* __restrict__ w_ma, const float* __restrict__ b_ma,
    const float* __restrict__ w_mi, const float* __restrict__ b_mi,
    float* __restrict__ out)            // act_seq (B*T) then idm (B*5)
{
    const int b   = blockIdx.x;
    const int tid = threadIdx.x;
    const int w   = tid >> 6;           // wave 0 or 1
    const int l   = tid & 63;
    const int cl  = (l < U) ? l : (U - 1);

    __shared__ __align__(16) float4 xlds[TT];        // staged x(b,:,:)  1600B
    __shared__ __align__(16) _Float16 h16[64];       // h state (f16)
    __shared__ __align__(8)  float2 zex[64];         // {tanh(zg), sig(zo)}
    __shared__ float idm[8];

    // ---- per-lane weights: gates g0=2w, g1=2w+1, column cl ----
    uint32_t wpk[2][25];
    #pragma unroll
    for (int gi = 0; gi < 2; ++gi) {
        const int g = 2 * w + gi;
        #pragma unroll
        for (int j = 0; j < 25; ++j) {
            float r0 = rec[(2 * j) * 200 + g * U + cl];
            float r1 = rec[(2 * j + 1) * 200 + g * U + cl];
            half2v p; p.x = (_Float16)r0; p.y = (_Float16)r1;
            wpk[gi][j] = __builtin_bit_cast(uint32_t, p);
        }
    }
    #pragma unroll
    for (int gi = 0; gi < 2; ++gi)
        #pragma unroll
        for (int j = 0; j < 25; ++j) asm volatile("" : "+v"(wpk[gi][j]));

    float kc[2][4];
    #pragma unroll
    for (int gi = 0; gi < 2; ++gi)
        #pragma unroll
        for (int f = 0; f < 4; ++f)
            kc[gi][f] = kernel[f * 200 + (2 * w + gi) * U + cl];
    float bz[2];
    #pragma unroll
    for (int gi = 0; gi < 2; ++gi) bz[gi] = bias[(2 * w + gi) * U + cl];

    // ---- stage x into LDS (no VMEM inside the loop!), init h ----
    const float4* __restrict__ xg = (const float4*)(x + (size_t)b * TT * 4);
    if (tid < TT) xlds[tid] = xg[tid];
    if (w == 0) h16[l] = (_Float16)0.0f;
    __syncthreads();

    float cstate = 0.0f;
    uint32_t hvu[25];
    #pragma unroll
    for (int j = 0; j < 25; ++j) hvu[j] = 0u;   // h(0) = 0

    const uint4* __restrict__ hq = (const uint4*)h16;
    const uint32_t* __restrict__ hd = (const uint32_t*)h16;

    for (int t = 0; t < TT; ++t) {
        float4 x4 = xlds[t];   // broadcast ds_read_b128

        // x-part for this wave's two gates
        float zx0 = fmaf(x4.x, kc[0][0], fmaf(x4.y, kc[0][1],
                    fmaf(x4.z, kc[0][2], fmaf(x4.w, kc[0][3], bz[0]))));
        float zx1 = fmaf(x4.x, kc[1][0], fmaf(x4.y, kc[1][1],
                    fmaf(x4.z, kc[1][2], fmaf(x4.w, kc[1][3], bz[1]))));

        // 50 dot2, 4 interleaved chains
        float a0 = 0.f, a1 = 0.f, a2 = 0.f, a3 = 0.f;
        #pragma unroll
        for (int j = 0; j < 25; j += 2) {
            a0 = dot2_acc(hvu[j], wpk[0][j], a0);
            a1 = dot2_acc(hvu[j], wpk[1][j], a1);
            if (j + 1 < 25) {
                a2 = dot2_acc(hvu[j + 1], wpk[0][j + 1], a2);
                a3 = dot2_acc(hvu[j + 1], wpk[1][j + 1], a3);
            }
        }
        float z0 = zx0 + a0 + a2;
        float z1 = zx1 + a1 + a3;

        float ig = 0.f, fg = 0.f;
        if (w == 1) {
            float gg = tanh_fast(z0);      // gate g
            float og = sigmoid_fast(z1);   // gate o
            zex[l] = make_float2(gg, og);  // ds_write_b64
        } else {
            ig = sigmoid_fast(z0);         // gate i
            fg = sigmoid_fast(z1);         // gate f
        }
        __syncthreads();                   // zex visible
        if (w == 0) {
            float2 go = zex[l];            // ds_read_b64
            cstate = fmaf(fg, cstate, ig * go.x);
            float hn = go.y * tanh_fast(cstate);
            if (l < U) h16[l] = (_Float16)hn;
        }
        __syncthreads();                   // h(t+1) visible

        // reload packed h for next step (latency overlaps next x-part/zx)
        #pragma unroll
        for (int q = 0; q < 6; ++q) {
            uint4 v = hq[q];
            hvu[4 * q + 0] = v.x; hvu[4 * q + 1] = v.y;
            hvu[4 * q + 2] = v.z; hvu[4 * q + 3] = v.w;
        }
        hvu[24] = hd[24];
    }

    // ---- 5 output heads (threads 0..4, wave 0) ----
    if (tid < 5) {
        const float* wv = (tid == 0) ? w_dv : (tid == 1) ? w_dt :
                          (tid == 2) ? w_mj : (tid == 3) ? w_ma : w_mi;
        const float* bv = (tid == 0) ? b_dv : (tid == 1) ? b_dt :
                          (tid == 2) ? b_mj : (tid == 3) ? b_ma : b_mi;
        float s = bv[0];
        #pragma unroll
        for (int j = 0; j < U; ++j) s = fmaf((float)h16[j], wv[j], s);
        float v;
        if (tid == 0)      v = param_act(s, 15.0f, 35.0f);
        else if (tid == 1) v = param_act(s, 0.5f, 3.0f);
        else if (tid == 2) v = fmaxf(s, 0.0f);
        else if (tid == 3) v = param_act(s, 0.5f, 3.0f);
        else               v = param_act(s, 0.5f, 4.0f);
        idm[tid] = v;
        out[BB * TT + b * 5 + tid] = v;
    }
    __syncthreads();

    // ---- IDM physics over T (128 threads) ----
    const float desired_v    = idm[0];
    const float desired_tgap = idm[1];
    const float min_jamx     = idm[2];
    const float max_act      = idm[3];
    const float min_act      = idm[4];
    const float inv_tsab = 1.0f / (2.0f * sqrtf(max_act * min_act));
    const float inv_dv   = 1.0f / desired_v;

    const float4* __restrict__ sb4 = (const float4*)(state + (size_t)b * TT * 4);
    for (int t = tid; t < TT; t += 128) {
        float4 s4 = sb4[t];
        float vel = s4.x;
        float dv  = s4.z;
        float dx  = s4.w;
        float dgap = fmaf(desired_tgap, vel, fmaf(vel * dv, inv_tsab, min_jamx));
        float r1 = vel * inv_dv;
        r1 = r1 * r1;
        r1 = r1 * r1;            // ^4
        float r2 = dgap / dx;
        r2 = r2 * r2;            // ^2
        out[b * TT + t] = max_act * (1.0f - (r1 + r2));
    }
}

extern "C" void kernel_launch(void* const* d_in, const int* in_sizes, int n_in,
                              void* d_out, int out_size, void* d_ws, size_t ws_size,
                              hipStream_t stream) {
    const float* x      = (const float*)d_in[0];
    const float* state  = (const float*)d_in[1];
    const float* kern   = (const float*)d_in[2];
    const float* rec    = (const float*)d_in[3];
    const float* bias   = (const float*)d_in[4];
    const float* w_dv   = (const float*)d_in[5];
    const float* b_dv   = (const float*)d_in[6];
    const float* w_dt   = (const float*)d_in[7];
    const float* b_dt   = (const float*)d_in[8];
    const float* w_mj   = (const float*)d_in[9];
    const float* b_mj   = (const float*)d_in[10];
    const float* w_ma   = (const float*)d_in[11];
    const float* b_ma   = (const float*)d_in[12];
    const float* w_mi   = (const float*)d_in[13];
    const float* b_mi   = (const float*)d_in[14];
    float* out = (float*)d_out;

    encoder_kernel<<<BB, 128, 0, stream>>>(
        x, state, kern, rec, bias,
        w_dv, b_dv, w_dt, b_dt, w_mj, b_mj, w_ma, b_ma, w_mi, b_mi,
        out);
}

// Round 14
// 44.814 us; speedup vs baseline: 2.1604x; 1.1170x over previous
//
#include <hip/hip_runtime.h>
#include <hip/hip_fp16.h>
#include <math.h>
#include <stdint.h>

#define U 50
#define TT 100
#define BB 256

typedef _Float16 half2v __attribute__((ext_vector_type(2)));

__device__ __forceinline__ float dot2_acc(uint32_t h2, uint32_t w2, float c) {
#if __has_builtin(__builtin_amdgcn_fdot2)
    return __builtin_amdgcn_fdot2(__builtin_bit_cast(half2v, h2),
                                  __builtin_bit_cast(half2v, w2), c, false);
#else
    half2v a = __builtin_bit_cast(half2v, h2);
    half2v b = __builtin_bit_cast(half2v, w2);
    return fmaf((float)a.x, (float)b.x, fmaf((float)a.y, (float)b.y, c));
#endif
}

__device__ __forceinline__ float sigmoid_fast(float x) {
    return 1.0f / (1.0f + __expf(-x));   // saturates cleanly, no NaN
}
__device__ __forceinline__ float tanh_fast(float x) {
    float e = __expf(2.0f * x);
    return 1.0f - 2.0f / (e + 1.0f);     // saturates cleanly, no NaN
}
__device__ __forceinline__ float param_act(float x, float mn, float mx) {
    float scale = 0.5f * (mx - mn);
    return tanh_fast(x) * scale + mn + scale;
}

// FOUR waves per batch element; wave w owns gate w (0=i,1=f,2=g,3=o) of unit
// l. Per-lane weight footprint: 25 packed dwords (+kc,bz) -- inside the
// residency envelope the counters showed (~60-80). ONE barrier per step:
// each wave applies its own nonlinearity pre-barrier and writes one float of
// the double-buffered zex[t&1][l]; post-barrier ALL waves redundantly run the
// c/h chain (identical inputs -> identical values; 4x same-value h16 writes
// are benign), so each wave sees its own h writes in order and reloads hvu
// without a second barrier. x pre-staged in LDS -> zero VMEM in the loop.
__global__ __launch_bounds__(256, 1) void encoder_kernel(
    const float* __restrict__ x,        // (B,T,4)
    const float* __restrict__ state,    // (B,T,4)
    const float* __restrict__ kernel,   // (4,200)
    const float* __restrict__ rec,      // (50,200)
    const float* __restrict__ bias,     // (200,)
    const float* __restrict__ w_dv, const float* __restrict__ b_dv,
    const float* __restrict__ w_dt, const float* __restrict__ b_dt,
    const float* __restrict__ w_mj, const float* __restrict__ b_mj,
    const float* __restrict__ w_ma, const float* __restrict__ b_ma,
    const float* __restrict__ w_mi, const float* __restrict__ b_mi,
    float* __restrict__ out)            // act_seq (B*T) then idm (B*5)
{
    const int b   = blockIdx.x;
    const int tid = threadIdx.x;
    const int w   = tid >> 6;           // gate owned by this wave (0..3)
    const int l   = tid & 63;
    const int cl  = (l < U) ? l : (U - 1);

    __shared__ __align__(16) float4 xlds[TT];        // staged x(b,:,:)  1600B
    __shared__ __align__(16) _Float16 h16[64];       // h state (f16)
    __shared__ __align__(16) float4 zex[2][64];      // dbuf {i,f,g,o} nonlin
    __shared__ float idm[8];

    // ---- per-lane weights: gate w, column cl -- 25 packed dwords ----
    uint32_t wpk[25];
    #pragma unroll
    for (int j = 0; j < 25; ++j) {
        float r0 = rec[(2 * j) * 200 + w * U + cl];
        float r1 = rec[(2 * j + 1) * 200 + w * U + cl];
        half2v p; p.x = (_Float16)r0; p.y = (_Float16)r1;
        wpk[j] = __builtin_bit_cast(uint32_t, p);
    }
    #pragma unroll
    for (int j = 0; j < 25; ++j) asm volatile("" : "+v"(wpk[j]));

    float kc[4];
    #pragma unroll
    for (int f = 0; f < 4; ++f) kc[f] = kernel[f * 200 + w * U + cl];
    float bz = bias[w * U + cl];

    // ---- stage x into LDS (zero VMEM in the loop), init h ----
    const float4* __restrict__ xg = (const float4*)(x + (size_t)b * TT * 4);
    if (tid < TT) xlds[tid] = xg[tid];
    if (tid < 64) h16[tid] = (_Float16)0.0f;
    __syncthreads();

    float cstate = 0.0f;
    uint32_t hvu[25];
    #pragma unroll
    for (int j = 0; j < 25; ++j) hvu[j] = 0u;   // h(0) = 0

    const uint4* __restrict__ hq = (const uint4*)h16;
    const uint32_t* __restrict__ hd = (const uint32_t*)h16;

    for (int t = 0; t < TT; ++t) {
        float4 x4 = xlds[t];   // broadcast ds_read_b128

        // z for this wave's gate: x-part + 25 dot2 (2 chains)
        float z = fmaf(x4.x, kc[0], fmaf(x4.y, kc[1],
                  fmaf(x4.z, kc[2], fmaf(x4.w, kc[3], bz))));
        float a0 = 0.f, a1 = 0.f;
        #pragma unroll
        for (int j = 0; j < 24; j += 2) {
            a0 = dot2_acc(hvu[j], wpk[j], a0);
            a1 = dot2_acc(hvu[j + 1], wpk[j + 1], a1);
        }
        a0 = dot2_acc(hvu[24], wpk[24], a0);
        z += a0 + a1;

        // own gate's nonlinearity (4 exps run in parallel across waves)
        float nl = (w == 2) ? tanh_fast(z) : sigmoid_fast(z);
        ((float*)&zex[t & 1][l])[w] = nl;   // write own component (4B)

        __syncthreads();                     // zex(t) complete

        // redundant c/h chain on ALL waves (identical data -> identical bits)
        float4 g4 = zex[t & 1][l];           // {i,f,g,o}
        cstate = fmaf(g4.y, cstate, g4.x * g4.z);
        float hn = g4.w * tanh_fast(cstate);
        if (l < U) h16[l] = (_Float16)hn;    // 4x same-value write: benign

        // reload packed h(t+1); own-wave write->read is in-order (lgkmcnt)
        #pragma unroll
        for (int q = 0; q < 6; ++q) {
            uint4 v = hq[q];
            hvu[4 * q + 0] = v.x; hvu[4 * q + 1] = v.y;
            hvu[4 * q + 2] = v.z; hvu[4 * q + 3] = v.w;
        }
        hvu[24] = hd[24];
        // next iteration writes zex[(t+1)&1] -- the OTHER buffer, so no
        // second barrier is needed before overwriting.
    }

    // ---- 5 output heads (threads 0..4; wave 0 wrote h16 itself) ----
    if (tid < 5) {
        const float* wv = (tid == 0) ? w_dv : (tid == 1) ? w_dt :
                          (tid == 2) ? w_mj : (tid == 3) ? w_ma : w_mi;
        const float* bv = (tid == 0) ? b_dv : (tid == 1) ? b_dt :
                          (tid == 2) ? b_mj : (tid == 3) ? b_ma : b_mi;
        float s = bv[0];
        #pragma unroll
        for (int j = 0; j < U; ++j) s = fmaf((float)h16[j], wv[j], s);
        float v;
        if (tid == 0)      v = param_act(s, 15.0f, 35.0f);
        else if (tid == 1) v = param_act(s, 0.5f, 3.0f);
        else if (tid == 2) v = fmaxf(s, 0.0f);
        else if (tid == 3) v = param_act(s, 0.5f, 3.0f);
        else               v = param_act(s, 0.5f, 4.0f);
        idm[tid] = v;
        out[BB * TT + b * 5 + tid] = v;
    }
    __syncthreads();

    // ---- IDM physics over T (256 threads) ----
    const float desired_v    = idm[0];
    const float desired_tgap = idm[1];
    const float min_jamx     = idm[2];
    const float max_act      = idm[3];
    const float min_act      = idm[4];
    const float inv_tsab = 1.0f / (2.0f * sqrtf(max_act * min_act));
    const float inv_dv   = 1.0f / desired_v;

    const float4* __restrict__ sb4 = (const float4*)(state + (size_t)b * TT * 4);
    for (int t = tid; t < TT; t += 256) {
        float4 s4 = sb4[t];
        float vel = s4.x;
        float dv  = s4.z;
        float dx  = s4.w;
        float dgap = fmaf(desired_tgap, vel, fmaf(vel * dv, inv_tsab, min_jamx));
        float r1 = vel * inv_dv;
        r1 = r1 * r1;
        r1 = r1 * r1;            // ^4
        float r2 = dgap / dx;
        r2 = r2 * r2;            // ^2
        out[b * TT + t] = max_act * (1.0f - (r1 + r2));
    }
}

extern "C" void kernel_launch(void* const* d_in, const int* in_sizes, int n_in,
                              void* d_out, int out_size, void* d_ws, size_t ws_size,
                              hipStream_t stream) {
    const float* x      = (const float*)d_in[0];
    const float* state  = (const float*)d_in[1];
    const float* kern   = (const float*)d_in[2];
    const float* rec    = (const float*)d_in[3];
    const float* bias   = (const float*)d_in[4];
    const float* w_dv   = (const float*)d_in[5];
    const float* b_dv   = (const float*)d_in[6];
    const float* w_dt   = (const float*)d_in[7];
    const float* b_dt   = (const float*)d_in[8];
    const float* w_mj   = (const float*)d_in[9];
    const float* b_mj   = (const float*)d_in[10];
    const float* w_ma   = (const float*)d_in[11];
    const float* b_ma   = (const float*)d_in[12];
    const float* w_mi   = (const float*)d_in[13];
    const float* b_mi   = (const float*)d_in[14];
    float* out = (float*)d_out;

    encoder_kernel<<<BB, 256, 0, stream>>>(
        x, state, kern, rec, bias,
        w_dv, b_dv, w_dt, b_dt, w_mj, b_mj, w_ma, b_ma, w_mi, b_mi,
        out);
}